// Round 10
// baseline (72.641 us; speedup 1.0000x reference)
//
#include <hip/hip_runtime.h>
#include <hip/hip_bf16.h>

// ConvexWidthUpsampler, all-MFMA, persistent-wave, transposed round-2,
// hi-only bf16 weights (24 MFMAs/tile/wave), clamped-address x loads.
// Row (128B, XOR-swizzled 16B blocks): k0..8=xv, k9=1, k10..31=0, k32..63=|z|.
// Round 1 (transposed): z[n,px] = mfma(B1, a0); |z| bf16 -> bytes 64..127.
// Round 2 (transposed): m[n,px] = mfma(B2, a_kt); one f32x4 scatter per nt.
// Persistent grid (2048 blocks, 8 tiles each), x prefetch 1 tile ahead.
// B=16,C=1,H=512,W=512,up=(1,3). Output [16,1,512,1536] f32.

#define BB 16
#define HH 512
#define WW 512
#define HID 32
#define NM 27
#define LOG2E 1.44269504088896340736f
#define NT 16384     // total 256-pixel tiles
#define NBLK 2048    // 8 per CU; NT/NBLK = 8 tiles per block

typedef short bf16x8 __attribute__((ext_vector_type(8)));
typedef float f32x4  __attribute__((ext_vector_type(4)));
typedef unsigned int u32;
typedef u32 u32x4 __attribute__((ext_vector_type(4)));
typedef u32 u32x2 __attribute__((ext_vector_type(2)));

__device__ __forceinline__ u32 pk2(float a, float b) {
    union { __hip_bfloat162 h2; u32 u; } cv;
    cv.h2 = __float22bfloat162_rn(make_float2(a, b));
    return cv.u;
}

// Compiler memory fence (free at runtime): blocks CSE/reordering of LDS ops
// across stages; HW DS ops within a wave execute in issue order.
__device__ __forceinline__ void lds_fence() {
    asm volatile("" ::: "memory");
    __builtin_amdgcn_sched_barrier(0);
}

// Clamped-address 3x3 load: addresses always in-bounds, zeros via cndmask.
__device__ __forceinline__ void load_xv(const float* __restrict__ x, int tile,
                                        int tid, float xv[9]) {
    const int p    = tile * 256 + tid;
    const int wcol = p & (WW - 1);
    const int t    = p >> 9;
    const int hrow = t & (HH - 1);
    const int bidx = t >> 9;
    const float* xb = x + (size_t)bidx * (HH * WW);
    int hy[3], wx[3];
    bool hok[3], wok[3];
#pragma unroll
    for (int i = 0; i < 3; ++i) {
        const int h = hrow + i - 1;
        hok[i] = (unsigned)h < (unsigned)HH;
        hy[i]  = h < 0 ? 0 : (h > HH - 1 ? HH - 1 : h);
        const int w = wcol + i - 1;
        wok[i] = (unsigned)w < (unsigned)WW;
        wx[i]  = w < 0 ? 0 : (w > WW - 1 ? WW - 1 : w);
    }
#pragma unroll
    for (int ki = 0; ki < 3; ++ki)
#pragma unroll
        for (int kj = 0; kj < 3; ++kj) {
            const float v = xb[hy[ki] * WW + wx[kj]];
            xv[ki * 3 + kj] = (hok[ki] && wok[kj]) ? v : 0.0f;
        }
}

// ws bf16 layout (identical to R7/R9, replay-proven; lo terms still written
// but no longer loaded by the main kernel):
//   [0..4095]    B2 [tm][32 n][64 k], log2e-scaled: k<9 M1, k==9 bias', k>=32 M2[k-32]
//   [4096..6143] B1 [tm][32 n][32 k], raw: k<9 w1[n][k], k==9 b1[n], else 0
__global__ void prep_B(const float* __restrict__ w1, const float* __restrict__ b1,
                       const float* __restrict__ alpha, const float* __restrict__ w2,
                       const float* __restrict__ b2, __hip_bfloat16* __restrict__ ws) {
    const int i = blockIdx.x * 256 + threadIdx.x;
    if (i >= 6144) return;
    float v = 0.0f;
    int tm;
    if (i < 4096) {
        tm = i >> 11;
        const int r = i & 2047, n = r >> 6, k = r & 63;
        if (n < NM) {
            if (k < 9) {
                for (int c = 0; c < HID; ++c)
                    v += w2[n * HID + c] * (0.5f * (1.0f + alpha[c])) * w1[c * 9 + k];
            } else if (k == 9) {
                v = b2[n];
                for (int c = 0; c < HID; ++c)
                    v += w2[n * HID + c] * (0.5f * (1.0f + alpha[c])) * b1[c];
            } else if (k >= 32) {
                const int c = k - 32;
                v = w2[n * HID + c] * (0.5f * (1.0f - alpha[c]));
            }
        }
        v *= LOG2E;
    } else {
        const int j = i - 4096;
        tm = j >> 10;
        const int r = j & 1023, n = r >> 5, k = r & 31;
        v = (k < 9) ? w1[n * 9 + k] : (k == 9 ? b1[n] : 0.0f);
    }
    const float hi = __bfloat162float(__float2bfloat16(v));
    ws[i] = __float2bfloat16(tm == 0 ? v : v - hi);
}

__global__ __launch_bounds__(256, 4) void convex_upsample_mfma6(
    const float* __restrict__ x,            // [16,1,512,512]
    const __hip_bfloat16* __restrict__ ws,  // prep output
    float* __restrict__ out)                // [16,1,512,1536]
{
    __shared__ char lds_raw[4][64 * 128];   // 32 KB/block

    const int tid  = threadIdx.x;
    const int wv   = tid >> 6;
    const int lane = tid & 63;
    const int l16  = lane & 15;
    const int lq   = lane >> 4;
    char* wbase = lds_raw[wv];
    const int sx  = (lane & 7) << 4;
    const int asx = (l16 & 7) << 4;

    // persistent weight fragments, HI term only:
    // lane holds n = nt*16+l16, k = kt*32 + lq*8 + i
    bf16x8 Bf2[2][2];   // [kt][nt]
    bf16x8 Bf1[2];      // [nt]
#pragma unroll
    for (int nt = 0; nt < 2; ++nt) {
#pragma unroll
        for (int kt = 0; kt < 2; ++kt)
            Bf2[kt][nt] = *(const bf16x8*)(ws + (nt * 16 + l16) * 64 + kt * 32 + lq * 8);
        Bf1[nt] = *(const bf16x8*)(ws + 4096 + (nt * 16 + l16) * 32 + lq * 8);
    }

    int tb = blockIdx.x;
    float xv[9];
    load_xv(x, tb, tid, xv);

    while (tb < NT) {
        const int tn  = tb + NBLK;
        const int tpf = (tn < NT) ? tn : 0;   // valid-address prefetch target
        float xn[9];
        load_xv(x, tpf, tid, xn);             // in flight during this tile's compute

        // ---- init my row, bytes 0..63: xv(9), 1.0, zeros ----
        char* myrow = wbase + lane * 128;
        *(u32x4*)(myrow + (0 ^ sx))  = (u32x4){pk2(xv[0], xv[1]), pk2(xv[2], xv[3]),
                                               pk2(xv[4], xv[5]), pk2(xv[6], xv[7])};
        *(u32x4*)(myrow + (16 ^ sx)) = (u32x4){pk2(xv[8], 1.0f), 0u, 0u, 0u};
        *(u32x4*)(myrow + (32 ^ sx)) = (u32x4){0u, 0u, 0u, 0u};
        *(u32x4*)(myrow + (48 ^ sx)) = (u32x4){0u, 0u, 0u, 0u};

        lds_fence();   // init writes -> round-1 cross-lane reads

        // ---- round 1: z[n,px] (transposed, hi); |z| bf16 -> bytes 64..127 ----
        bf16x8 a0[4];
#pragma unroll
        for (int mt = 0; mt < 4; ++mt) {
            char* ab = wbase + (mt * 16 + l16) * 128;
            a0[mt] = *(const bf16x8*)(ab + ((lq * 16) ^ asx));   // k0..31 (xv,1,0)
            f32x4 z0 = {0.f, 0.f, 0.f, 0.f}, z1 = {0.f, 0.f, 0.f, 0.f};
            z0 = __builtin_amdgcn_mfma_f32_16x16x32_bf16(Bf1[0], a0[mt], z0, 0, 0, 0);
            z1 = __builtin_amdgcn_mfma_f32_16x16x32_bf16(Bf1[1], a0[mt], z1, 0, 0, 0);
            // lane holds z[n], n = nt*16 + lq*4 + r, for pixel mt*16 + l16
            const u32x2 d0 = (u32x2){pk2(fabsf(z0[0]), fabsf(z0[1])), pk2(fabsf(z0[2]), fabsf(z0[3]))};
            const u32x2 d1 = (u32x2){pk2(fabsf(z1[0]), fabsf(z1[1])), pk2(fabsf(z1[2]), fabsf(z1[3]))};
            const int nb0 = 64 + lq * 8;    // ch lq*4..+3    -> byte 64+2n
            const int nb1 = 96 + lq * 8;    // ch 16+lq*4..+3
            *(u32x2*)(ab + ((nb0 & 0x70) ^ asx) + (nb0 & 15)) = d0;
            *(u32x2*)(ab + ((nb1 & 0x70) ^ asx) + (nb1 & 15)) = d1;
        }

        lds_fence();   // z writes -> round-2 a1 reads

        // ---- round 2 (transposed): m[n,px]; lane = 4 consecutive n, 1 pixel ----
#pragma unroll
        for (int mt = 0; mt < 4; ++mt) {
            char* ab = wbase + (mt * 16 + l16) * 128;
            const bf16x8 a1 = *(const bf16x8*)(ab + ((64 + lq * 16) ^ asx));   // k32..63 = |z|
            f32x4 c0 = {0.f, 0.f, 0.f, 0.f}, c1 = {0.f, 0.f, 0.f, 0.f};
            c0 = __builtin_amdgcn_mfma_f32_16x16x32_bf16(Bf2[0][0], a0[mt], c0, 0, 0, 0);
            c0 = __builtin_amdgcn_mfma_f32_16x16x32_bf16(Bf2[1][0], a1,     c0, 0, 0, 0);
            c1 = __builtin_amdgcn_mfma_f32_16x16x32_bf16(Bf2[0][1], a0[mt], c1, 0, 0, 0);
            c1 = __builtin_amdgcn_mfma_f32_16x16x32_bf16(Bf2[1][1], a1,     c1, 0, 0, 0);
            // D[n][px]: lane (l16,lq) holds n = nt*16 + lq*4 + r for pixel mt*16+l16
            *(f32x4*)(ab + ((lq * 16) ^ asx))      = c0;   // n = lq*4..+3
            *(f32x4*)(ab + ((64 + lq * 16) ^ asx)) = c1;   // n = 16+lq*4..+3
        }

        lds_fence();   // m scatter -> readback

        // ---- readback 27 logits + softmax + convex combine + store ----
        f32x4 mv[7];
#pragma unroll
        for (int q = 0; q < 7; ++q)
            mv[q] = *(const f32x4*)(myrow + ((q * 16) ^ sx));

        const int p    = tb * 256 + tid;
        const int wcol = p & (WW - 1);
        const int t    = p >> 9;
        const int hrow = t & (HH - 1);
        const int bidx = t >> 9;
        const size_t ob = ((size_t)(bidx * HH + hrow) * (WW * 3)) + (size_t)wcol * 3;
#pragma unroll
        for (int v = 0; v < 3; ++v) {
            float ssum = 0.0f, acc = 0.0f;
#pragma unroll
            for (int k = 0; k < 9; ++k) {
                const int j = k * 3 + v;
                const float e = __builtin_amdgcn_exp2f(mv[j >> 2][j & 3]);
                ssum += e;
                acc = fmaf(xv[k], e, acc);
            }
            out[ob + v] = acc * __builtin_amdgcn_rcpf(ssum);
        }

        lds_fence();   // readback reads -> next iteration's init writes

        tb = tn;
#pragma unroll
        for (int k = 0; k < 9; ++k) xv[k] = xn[k];
    }
}

extern "C" void kernel_launch(void* const* d_in, const int* in_sizes, int n_in,
                              void* d_out, int out_size, void* d_ws, size_t ws_size,
                              hipStream_t stream) {
    // setup_inputs order: x, target_h, target_w, w1, b1, alpha, w2, b2
    const float* x     = (const float*)d_in[0];
    const float* w1    = (const float*)d_in[3];
    const float* b1    = (const float*)d_in[4];
    const float* alpha = (const float*)d_in[5];
    const float* w2    = (const float*)d_in[6];
    const float* b2    = (const float*)d_in[7];
    float* out = (float*)d_out;
    __hip_bfloat16* ws = (__hip_bfloat16*)d_ws;   // 6144 bf16 = 12 KB

    hipLaunchKernelGGL(prep_B, dim3(24), dim3(256), 0, stream, w1, b1, alpha, w2, b2, ws);
    hipLaunchKernelGGL(convex_upsample_mfma6, dim3(NBLK), dim3(256), 0, stream,
                       x, ws, out);
}

// Round 11
// 67.174 us; speedup vs baseline: 1.0814x; 1.0814x over previous
//
#include <hip/hip_runtime.h>
#include <hip/hip_bf16.h>

// ConvexWidthUpsampler R11: z stays IN REGISTERS (permuted-M2 trick).
// Round 1: z[n,px] = mfma(B1, a0)  (D-frag: lane(l16,lq) = z[lq*4+r][l16]).
// zfrag = packed |z| bf16x8 is a legal B-operand under channel perm
// pi(k) = (k&4?16:0) + (k>>3)*4 + (k&3); prep builds M2p[n][k]=M2[n][pi(k)].
// Round 2: m = mfma(M2p, zfrag) + mfma(B2, a0)  -- no z LDS roundtrip.
// Row (128B, XOR-swizzled): bytes 0..31 = k0..15 (xv,1,0), k16..31 read from
// a broadcast-zero block. Scatter: c1(n16..31)->bytes 0..63, c0(n0..15)->64..127.
// Persistent grid (2048 blocks, 8 tiles), x prefetch 1 tile ahead.
// B=16,C=1,H=512,W=512,up=(1,3). Output [16,1,512,1536] f32.

#define BB 16
#define HH 512
#define WW 512
#define HID 32
#define NM 27
#define LOG2E 1.44269504088896340736f
#define NT 16384
#define NBLK 2048
#define ZOFF 8192   // per-wave broadcast-zero block offset

typedef short bf16x8 __attribute__((ext_vector_type(8)));
typedef float f32x4  __attribute__((ext_vector_type(4)));
typedef unsigned int u32;
typedef u32 u32x4 __attribute__((ext_vector_type(4)));

__device__ __forceinline__ u32 pk2(float a, float b) {
    union { __hip_bfloat162 h2; u32 u; } cv;
    cv.h2 = __float22bfloat162_rn(make_float2(a, b));
    return cv.u;
}

// Compiler memory fence (free at runtime): blocks CSE/TBAA reordering of LDS
// ops across stages; a wave's DS instructions execute in issue order in HW.
__device__ __forceinline__ void lds_fence() {
    asm volatile("" ::: "memory");
    __builtin_amdgcn_sched_barrier(0);
}

// Clamped-address 3x3 load: addresses always in-bounds, zeros via cndmask.
__device__ __forceinline__ void load_xv(const float* __restrict__ x, int tile,
                                        int tid, float xv[9]) {
    const int p    = tile * 256 + tid;
    const int wcol = p & (WW - 1);
    const int t    = p >> 9;
    const int hrow = t & (HH - 1);
    const int bidx = t >> 9;
    const float* xb = x + (size_t)bidx * (HH * WW);
    int hy[3], wx[3];
    bool hok[3], wok[3];
#pragma unroll
    for (int i = 0; i < 3; ++i) {
        const int h = hrow + i - 1;
        hok[i] = (unsigned)h < (unsigned)HH;
        hy[i]  = h < 0 ? 0 : (h > HH - 1 ? HH - 1 : h);
        const int w = wcol + i - 1;
        wok[i] = (unsigned)w < (unsigned)WW;
        wx[i]  = w < 0 ? 0 : (w > WW - 1 ? WW - 1 : w);
    }
#pragma unroll
    for (int ki = 0; ki < 3; ++ki)
#pragma unroll
        for (int kj = 0; kj < 3; ++kj) {
            const float v = xb[hy[ki] * WW + wx[kj]];
            xv[ki * 3 + kj] = (hok[ki] && wok[kj]) ? v : 0.0f;
        }
}

// ws bf16 layout (hi-only, 3072 elems = 6 KB):
//   [0   ..1023] B2_32 [32 n][32 k]: k<9 M1[n][k], k==9 bias'[n], else 0 (xlog2e)
//   [1024..2047] M2p   [32 n][32 k]: M2[n][pi(k)] (xlog2e), n>=27 -> 0
//   [2048..3071] B1    [32 n][32 k]: k<9 w1[n][k], k==9 b1[n], else 0
__global__ void prep_B(const float* __restrict__ w1, const float* __restrict__ b1,
                       const float* __restrict__ alpha, const float* __restrict__ w2,
                       const float* __restrict__ b2, __hip_bfloat16* __restrict__ ws) {
    const int i = blockIdx.x * 256 + threadIdx.x;
    if (i >= 3072) return;
    const int sec = i >> 10;
    const int r   = i & 1023;
    const int n   = r >> 5, k = r & 31;
    float v = 0.0f;
    if (sec == 0) {
        if (n < NM) {
            if (k < 9) {
                for (int c = 0; c < HID; ++c)
                    v += w2[n * HID + c] * (0.5f * (1.0f + alpha[c])) * w1[c * 9 + k];
            } else if (k == 9) {
                v = b2[n];
                for (int c = 0; c < HID; ++c)
                    v += w2[n * HID + c] * (0.5f * (1.0f + alpha[c])) * b1[c];
            }
        }
        v *= LOG2E;
    } else if (sec == 1) {
        if (n < NM) {
            const int c = ((k & 4) ? 16 : 0) + (k >> 3) * 4 + (k & 3);  // pi(k)
            v = w2[n * HID + c] * (0.5f * (1.0f - alpha[c])) * LOG2E;
        }
    } else {
        v = (k < 9) ? w1[n * 9 + k] : (k == 9 ? b1[n] : 0.0f);
    }
    ws[i] = __float2bfloat16(v);
}

__global__ __launch_bounds__(256, 4) void convex_upsample_mfma7(
    const float* __restrict__ x,            // [16,1,512,512]
    const __hip_bfloat16* __restrict__ ws,  // prep output
    float* __restrict__ out)                // [16,1,512,1536]
{
    __shared__ char lds_raw[4][ZOFF + 16];  // 64 rows x 128B + 16B zero block

    const int tid  = threadIdx.x;
    const int wv   = tid >> 6;
    const int lane = tid & 63;
    const int l16  = lane & 15;
    const int lq   = lane >> 4;
    char* wbase = lds_raw[wv];
    const int sx  = (lane & 7) << 4;
    const int asx = (l16 & 7) << 4;

    // persistent weight fragments (hi only): lane row n = nt*16+l16, k = lq*8+i
    bf16x8 Bf2[2], M2p[2], Bf1[2];
#pragma unroll
    for (int nt = 0; nt < 2; ++nt) {
        const int ro = (nt * 16 + l16) * 32 + lq * 8;
        Bf2[nt] = *(const bf16x8*)(ws + ro);
        M2p[nt] = *(const bf16x8*)(ws + 1024 + ro);
        Bf1[nt] = *(const bf16x8*)(ws + 2048 + ro);
    }

    // broadcast-zero block (idempotent per-wave write; read by lq>=2 a0 loads)
    *(u32x4*)(wbase + ZOFF) = (u32x4){0u, 0u, 0u, 0u};

    int tb = blockIdx.x;
    float xv[9];
    load_xv(x, tb, tid, xv);

    while (tb < NT) {
        const int tn  = tb + NBLK;
        const int tpf = (tn < NT) ? tn : 0;
        float xn[9];
        load_xv(x, tpf, tid, xn);   // prefetch next tile during this compute

        // ---- init my row bytes 0..31: k0..8=xv, k9=1, k10..15=0 ----
        char* myrow = wbase + lane * 128;
        *(u32x4*)(myrow + (0 ^ sx))  = (u32x4){pk2(xv[0], xv[1]), pk2(xv[2], xv[3]),
                                               pk2(xv[4], xv[5]), pk2(xv[6], xv[7])};
        *(u32x4*)(myrow + (16 ^ sx)) = (u32x4){pk2(xv[8], 1.0f), 0u, 0u, 0u};

        lds_fence();   // init writes -> cross-lane a0 reads

        // ---- hoisted a0 reads (latencies overlap); lq>=2 -> broadcast zeros ----
        bf16x8 a0[4];
#pragma unroll
        for (int mt = 0; mt < 4; ++mt) {
            char* ab = wbase + (mt * 16 + l16) * 128;
            const char* aptr = (lq < 2) ? (ab + ((lq * 16) ^ asx)) : (wbase + ZOFF);
            a0[mt] = *(const bf16x8*)aptr;
        }

        lds_fence();   // a0 reads -> scatters below (TBAA/reorder guard)

        // ---- per mt: z in-register -> logits -> scatter ----
#pragma unroll
        for (int mt = 0; mt < 4; ++mt) {
            char* ab = wbase + (mt * 16 + l16) * 128;
            // round 1: z[ch][px]; lane(l16,lq) gets ch = {lq*4+r, 16+lq*4+r}, px = l16
            f32x4 z0 = {0.f, 0.f, 0.f, 0.f}, z1 = {0.f, 0.f, 0.f, 0.f};
            z0 = __builtin_amdgcn_mfma_f32_16x16x32_bf16(Bf1[0], a0[mt], z0, 0, 0, 0);
            z1 = __builtin_amdgcn_mfma_f32_16x16x32_bf16(Bf1[1], a0[mt], z1, 0, 0, 0);
            // pack |z| as permuted B-operand fragment (k = lq*8+i -> ch pi(k))
            union { u32 u[4]; bf16x8 h; } zf;
            zf.u[0] = pk2(fabsf(z0[0]), fabsf(z0[1]));
            zf.u[1] = pk2(fabsf(z0[2]), fabsf(z0[3]));
            zf.u[2] = pk2(fabsf(z1[0]), fabsf(z1[1]));
            zf.u[3] = pk2(fabsf(z1[2]), fabsf(z1[3]));
            // round 2: logits m[n][px] = M2p*|z| + B2*a0
            f32x4 c0 = {0.f, 0.f, 0.f, 0.f}, c1 = {0.f, 0.f, 0.f, 0.f};
            c0 = __builtin_amdgcn_mfma_f32_16x16x32_bf16(M2p[0], zf.h,   c0, 0, 0, 0);
            c0 = __builtin_amdgcn_mfma_f32_16x16x32_bf16(Bf2[0], a0[mt], c0, 0, 0, 0);
            c1 = __builtin_amdgcn_mfma_f32_16x16x32_bf16(M2p[1], zf.h,   c1, 0, 0, 0);
            c1 = __builtin_amdgcn_mfma_f32_16x16x32_bf16(Bf2[1], a0[mt], c1, 0, 0, 0);
            // scatter: lane(l16,lq) holds n = lq*4..+3 (c0) / 16+lq*4..+3 (c1)
            // for pixel mt*16+l16.  c0 -> bytes 64..127, c1 -> bytes 0..63.
            *(f32x4*)(ab + ((64 + lq * 16) ^ asx)) = c0;
            *(f32x4*)(ab + ((lq * 16) ^ asx))      = c1;
        }

        lds_fence();   // scatters -> readback

        // ---- readback 27 logits: n0..15 @ bytes 64..127, n16..26 @ 0..47 ----
        f32x4 mv[7];
#pragma unroll
        for (int q = 0; q < 4; ++q)
            mv[q] = *(const f32x4*)(myrow + ((64 + q * 16) ^ sx));
#pragma unroll
        for (int q = 0; q < 3; ++q)
            mv[4 + q] = *(const f32x4*)(myrow + ((q * 16) ^ sx));

        const int p    = tb * 256 + tid;
        const int wcol = p & (WW - 1);
        const int t    = p >> 9;
        const int hrow = t & (HH - 1);
        const int bidx = t >> 9;
        const size_t ob = ((size_t)(bidx * HH + hrow) * (WW * 3)) + (size_t)wcol * 3;
#pragma unroll
        for (int v = 0; v < 3; ++v) {
            float ssum = 0.0f, acc = 0.0f;
#pragma unroll
            for (int k = 0; k < 9; ++k) {
                const int j = k * 3 + v;
                const float lg = (j < 16) ? mv[j >> 2][j & 3]
                                          : mv[4 + ((j - 16) >> 2)][(j - 16) & 3];
                const float e = __builtin_amdgcn_exp2f(lg);
                ssum += e;
                acc = fmaf(xv[k], e, acc);
            }
            out[ob + v] = acc * __builtin_amdgcn_rcpf(ssum);
        }

        lds_fence();   // readback -> next iteration's init writes

        tb = tn;
#pragma unroll
        for (int k = 0; k < 9; ++k) xv[k] = xn[k];
    }
}

extern "C" void kernel_launch(void* const* d_in, const int* in_sizes, int n_in,
                              void* d_out, int out_size, void* d_ws, size_t ws_size,
                              hipStream_t stream) {
    // setup_inputs order: x, target_h, target_w, w1, b1, alpha, w2, b2
    const float* x     = (const float*)d_in[0];
    const float* w1    = (const float*)d_in[3];
    const float* b1    = (const float*)d_in[4];
    const float* alpha = (const float*)d_in[5];
    const float* w2    = (const float*)d_in[6];
    const float* b2    = (const float*)d_in[7];
    float* out = (float*)d_out;
    __hip_bfloat16* ws = (__hip_bfloat16*)d_ws;   // 3072 bf16 = 6 KB

    hipLaunchKernelGGL(prep_B, dim3(12), dim3(256), 0, stream, w1, b1, alpha, w2, b2, ws);
    hipLaunchKernelGGL(convex_upsample_mfma7, dim3(NBLK), dim3(256), 0, stream,
                       x, ws, out);
}